// Round 2
// baseline (4586.670 us; speedup 1.0000x reference)
//
#include <hip/hip_runtime.h>
#include <hip/hip_bf16.h>
#include <stdint.h>

// ---------------------------------------------------------------------------
// BiLSTM-CRF on MI355X.  B=128, T=256, E=256, H2=256, NTAGS=76.
//   init_cnt   : zero cluster counters
//   build_a3   : embedding gather + split-bf16 (hi,hi,lo) A [32768 x 768]
//   build_b3t  : Wih both dirs split-bf16 (hi,lo,hi) B^T    [2048 x 768]
//   gemm_chunk : bf16 MFMA GEMM (3-term compensated == fp32-class) computing
//                xproj for a 64-step time chunk (both dirs) -> 64 MiB buffer
//   lstm_rec   : fp32 recurrence, 64 steps/launch. 256 WGs = 16 clusters x 16
//                hidden-slices; Whh slice register-resident; h exchanged via
//                agent-scope hbuf + per-cluster counter (XCD-swizzled).
//   out_proj   : feats = lstm_out @ W_out^T + b_out (fp32)
//   viterbi    : per-batch decode + backtrack -> score + path
// Workspace total ~180 MiB (checked against typical 256 MiB ws budgets).
// ---------------------------------------------------------------------------

#define T_      256
#define NT_     76
#define K3_     768
#define START_  74
#define STOP_   75
#define NEGV    (-10000.0f)

// ws offsets (bytes)
#define OFF_A3    ((size_t)0)                         // u16 [32768][768]   48 MiB
#define OFF_B3T   (OFF_A3    + (size_t)50331648)      // u16 [2048][768]     3 MiB
#define OFF_XPROJ (OFF_B3T   + (size_t)3145728)       // f32 [2][128][64][1024] 64 MiB
#define OFF_LSTM  (OFF_XPROJ + (size_t)67108864)      // f32 [32768][512]   64 MiB
#define OFF_HBUF  (OFF_LSTM  + (size_t)67108864)      // f32 [2][16][4096] 512 KiB
#define OFF_CBUF  (OFF_HBUF  + (size_t)524288)        // f32 [2][128][256] 256 KiB
#define OFF_CNT   (OFF_CBUF  + (size_t)262144)        // u32 x16, 256B stride
#define OFF_FEATS OFF_A3                              // f32 [32768][76] aliases A3

typedef __attribute__((ext_vector_type(8))) short short8;
typedef __attribute__((ext_vector_type(4))) float float4v;
typedef const __attribute__((address_space(1))) unsigned int gas_uint;
typedef __attribute__((address_space(3))) unsigned int las_uint;

__device__ __forceinline__ unsigned short f2bf(float x) {
    unsigned int u = __float_as_uint(x);
    u = (u + 0x7fffu + ((u >> 16) & 1u)) >> 16;   // RNE
    return (unsigned short)u;
}
__device__ __forceinline__ float bf2f(unsigned short h) {
    return __uint_as_float(((unsigned int)h) << 16);
}
__device__ __forceinline__ void gl_lds16(const void* g, void* l) {
    __builtin_amdgcn_global_load_lds((gas_uint*)g, (las_uint*)l, 16, 0, 0);
}

__global__ __launch_bounds__(64) void init_cnt(unsigned int* cnt) {
    if (threadIdx.x < 16) cnt[threadIdx.x * 64] = 0u;   // 256B stride
}

// ---------------------------------------------------------------------------
__global__ __launch_bounds__(256) void build_a3(const int* __restrict__ ids,
                                                const float* __restrict__ emb,
                                                unsigned short* __restrict__ a3) {
    int m = blockIdx.x, k = threadIdx.x;
    int id = ids[m];
    float x = emb[(size_t)id * 256 + k];
    unsigned short hu = f2bf(x);
    unsigned short lu = f2bf(x - bf2f(hu));
    size_t base = (size_t)m * K3_;
    a3[base + k]       = hu;
    a3[base + 256 + k] = hu;
    a3[base + 512 + k] = lu;
}

__global__ __launch_bounds__(256) void build_b3t(const float* __restrict__ wf,
                                                 const float* __restrict__ wb,
                                                 unsigned short* __restrict__ b3t) {
    int n = blockIdx.x, k = threadIdx.x;
    const float* w = (n < 1024) ? wf : wb;
    int j = n & 1023;
    float x = w[(size_t)j * 256 + k];
    unsigned short hu = f2bf(x);
    unsigned short lu = f2bf(x - bf2f(hu));
    size_t base = (size_t)n * K3_;
    b3t[base + k]       = hu;
    b3t[base + 256 + k] = lu;
    b3t[base + 512 + k] = hu;
}

// ---------------------------------------------------------------------------
// xproj chunk GEMM.  grid = 2 dirs x 64 m-tiles x 8 n-tiles = 1024 blocks.
// Per dir: M = 128b x 64t = 8192 rows, N = 1024, K = 768.
// A3 row for (b, tl) = b*256 + tbase + tl   (tbase = t0 fwd, 192-t0 bwd).
// C -> xproj[d][b][tl][n]  fp32.
// ---------------------------------------------------------------------------
__global__ __launch_bounds__(256) void gemm_chunk(const unsigned short* __restrict__ A,
                                                  const unsigned short* __restrict__ Bt,
                                                  float* __restrict__ C, int t0) {
    __shared__ __align__(16) unsigned short As[128 * 64];
    __shared__ __align__(16) unsigned short Bs[128 * 64];
    int tid = threadIdx.x, bx = blockIdx.x;
    int d = bx >> 9, rem = bx & 511;
    int tm = rem >> 3, tn = rem & 7;
    int m0 = tm * 128, n0l = tn * 128;
    int tbase = d ? (192 - t0) : t0;
    int lane = tid & 63, wave = tid >> 6;
    int wm = (wave & 1) * 64, wn = (wave >> 1) * 64;
    int quad = lane >> 4, r16 = lane & 15;

    float4v acc[4][4];
#pragma unroll
    for (int i = 0; i < 4; i++)
#pragma unroll
        for (int j = 0; j < 4; j++) acc[i][j] = (float4v){0.f, 0.f, 0.f, 0.f};

    for (int kt = 0; kt < 12; ++kt) {
        int k0 = kt * 64;
#pragma unroll
        for (int i = 0; i < 4; ++i) {
            int c = i * 256 + tid;            // 16B chunk id
            int row = c >> 3, col = c & 7;
            int rowm = m0 + row;
            int arow = (rowm >> 6) * 256 + tbase + (rowm & 63);
            int brow = d * 1024 + n0l + row;
            gl_lds16(A  + (size_t)arow * K3_ + k0 + col * 8, (unsigned short*)As + (size_t)c * 8);
            gl_lds16(Bt + (size_t)brow * K3_ + k0 + col * 8, (unsigned short*)Bs + (size_t)c * 8);
        }
        __syncthreads();
#pragma unroll
        for (int kk = 0; kk < 64; kk += 32) {
            short8 a[4], b[4];
#pragma unroll
            for (int i = 0; i < 4; i++) {
                a[i] = *(const short8*)&As[(wm + i * 16 + r16) * 64 + kk + quad * 8];
                b[i] = *(const short8*)&Bs[(wn + i * 16 + r16) * 64 + kk + quad * 8];
            }
#pragma unroll
            for (int i = 0; i < 4; i++)
#pragma unroll
                for (int j = 0; j < 4; j++)
                    acc[i][j] = __builtin_amdgcn_mfma_f32_16x16x32_bf16(a[i], b[j], acc[i][j], 0, 0, 0);
        }
        __syncthreads();
    }
    // C/D: m = quad*4 + reg, n = lane&15 (m89/m91-verified)
#pragma unroll
    for (int i = 0; i < 4; i++)
#pragma unroll
        for (int j = 0; j < 4; j++)
#pragma unroll
            for (int r = 0; r < 4; r++) {
                int ml = wm + i * 16 + quad * 4 + r;
                int rowm = m0 + ml;
                int b = rowm >> 6, tl = rowm & 63;
                int n = n0l + wn + j * 16 + r16;
                C[(((size_t)(d * 128 + b)) * 64 + tl) * 1024 + n] = acc[i][j][r];
            }
}

// ---------------------------------------------------------------------------
// Recurrence, 64 steps per launch.  256 WGs x 256 thr.
// XCD swizzle: cluster = blocks with same (bx&7), 16 members each.
// ---------------------------------------------------------------------------
#define HSTR 20

__global__ __launch_bounds__(256) void lstm_rec(
    const float* __restrict__ xproj,
    const float* __restrict__ whh_f, const float* __restrict__ whh_b,
    const float* __restrict__ bih_f, const float* __restrict__ bhh_f,
    const float* __restrict__ bih_b, const float* __restrict__ bhh_b,
    const float* __restrict__ h0,    const float* __restrict__ c0,
    float* __restrict__ lstm_out, float* hbuf, float* cbuf,
    unsigned char* cntbase, int t0) {

    int bx = blockIdx.x;
    int xcd = bx & 7, m8 = bx >> 3;          // m8 in [0,32)
    int cid = xcd * 2 + (m8 >> 4);           // cluster id [0,16)
    int s   = m8 & 15;                       // hidden-slice [0,16)
    int d   = cid & 1, g = cid >> 1;         // dir, batch-group
    int tid = threadIdx.x;

    // phase-B identity: wave q = k-quarter, lane r = gate*16 + ulocal
    int q = tid >> 6, r = tid & 63;
    int rowB = (r >> 4) * 256 + s * 16 + (r & 15);
    const float* whh = d ? whh_b : whh_f;
    float4 w4[16];
    {
        const float4* wp = (const float4*)(whh + (size_t)rowB * 256 + q * 64);
#pragma unroll
        for (int i = 0; i < 16; i++) w4[i] = wp[i];
    }

    // phase-C identity: (sample b2, unit u2)
    int b2 = tid >> 4, u2 = tid & 15;
    int ug2 = s * 16 + u2;
    int bg2 = g * 16 + b2;
    const float* bih = d ? bih_b : bih_f;
    const float* bhh = d ? bhh_b : bhh_f;
    float bias[4];
#pragma unroll
    for (int gg = 0; gg < 4; gg++) bias[gg] = bih[gg * 256 + ug2] + bhh[gg * 256 + ug2];
    size_t cidx = ((size_t)d * 128 + bg2) * 256 + ug2;
    float cst = (t0 == 0) ? c0[cidx] : cbuf[cidx];

    __shared__ __align__(16) float h_lds[256 * HSTR];
    __shared__ __align__(16) float red[4 * 64 * HSTR];

    unsigned int* mycnt = (unsigned int*)(cntbase + (size_t)cid * 256);
    const size_t HB_PAR = (size_t)16 * 4096;
    size_t hb_c = (size_t)cid * 4096;

    int bbS = tid >> 4, k0S = (tid & 15) * 16;   // staging identity

    for (int tl = 0; tl < 64; ++tl) {
        int t = t0 + tl;
        int tloc = d ? (63 - tl) : tl;
        int t_src = d ? (255 - t) : t;
        // xproj prefetch (independent of h)
        float xp[4];
        {
            const float* xb = xproj + (((size_t)(d * 128 + bg2)) * 64 + tloc) * 1024 + ug2;
#pragma unroll
            for (int gg = 0; gg < 4; gg++) xp[gg] = xb[gg * 256];
        }
        // stage h_t into LDS [k][b]
        if (t == 0) {
            const float* hsrc = h0 + ((size_t)d * 128 + g * 16 + bbS) * 256 + k0S;
#pragma unroll
            for (int i = 0; i < 16; i++) h_lds[(k0S + i) * HSTR + bbS] = hsrc[i];
        } else {
            float* hsrc = hbuf + (size_t)(t & 1) * HB_PAR + hb_c + (size_t)bbS * 256 + k0S;
#pragma unroll
            for (int i = 0; i < 16; i++)
                h_lds[(k0S + i) * HSTR + bbS] =
                    __hip_atomic_load(hsrc + i, __ATOMIC_RELAXED, __HIP_MEMORY_SCOPE_AGENT);
        }
        __syncthreads();

        // partial gates: acc[b] = sum_{k in quarter} w[k]*h[k][b]
        float acc[16];
#pragma unroll
        for (int b = 0; b < 16; b++) acc[b] = 0.f;
        const float* hq = h_lds + q * 64 * HSTR;
#pragma unroll
        for (int k4 = 0; k4 < 16; ++k4) {
            float4 wv = w4[k4];
#pragma unroll
            for (int kk = 0; kk < 4; ++kk) {
                float wx = (kk == 0) ? wv.x : (kk == 1) ? wv.y : (kk == 2) ? wv.z : wv.w;
                const float4* hv = (const float4*)(hq + (k4 * 4 + kk) * HSTR);
                float4 ha = hv[0], hb4 = hv[1], hc = hv[2], hd = hv[3];
                acc[0]  += wx * ha.x;  acc[1]  += wx * ha.y;  acc[2]  += wx * ha.z;  acc[3]  += wx * ha.w;
                acc[4]  += wx * hb4.x; acc[5]  += wx * hb4.y; acc[6]  += wx * hb4.z; acc[7]  += wx * hb4.w;
                acc[8]  += wx * hc.x;  acc[9]  += wx * hc.y;  acc[10] += wx * hc.z;  acc[11] += wx * hc.w;
                acc[12] += wx * hd.x;  acc[13] += wx * hd.y;  acc[14] += wx * hd.z;  acc[15] += wx * hd.w;
            }
        }
        {
            float4* rp = (float4*)&red[(q * 64 + r) * HSTR];
            rp[0] = make_float4(acc[0], acc[1], acc[2], acc[3]);
            rp[1] = make_float4(acc[4], acc[5], acc[6], acc[7]);
            rp[2] = make_float4(acc[8], acc[9], acc[10], acc[11]);
            rp[3] = make_float4(acc[12], acc[13], acc[14], acc[15]);
        }
        __syncthreads();

        float gate[4];
#pragma unroll
        for (int gg = 0; gg < 4; gg++) {
            int rr = gg * 16 + u2;
            gate[gg] = red[(0 * 64 + rr) * HSTR + b2] + red[(1 * 64 + rr) * HSTR + b2] +
                       red[(2 * 64 + rr) * HSTR + b2] + red[(3 * 64 + rr) * HSTR + b2] +
                       xp[gg] + bias[gg];
        }
        float iv = 1.f / (1.f + expf(-gate[0]));
        float fv = 1.f / (1.f + expf(-gate[1]));
        float gv = tanhf(gate[2]);
        float ov = 1.f / (1.f + expf(-gate[3]));
        cst = fv * cst + iv * gv;
        float hv = ov * tanhf(cst);

        __hip_atomic_store(hbuf + (size_t)((t + 1) & 1) * HB_PAR + hb_c + (size_t)b2 * 256 + ug2,
                           hv, __ATOMIC_RELAXED, __HIP_MEMORY_SCOPE_AGENT);
        lstm_out[((size_t)bg2 * 256 + t_src) * 512 + d * 256 + ug2] = hv;
        __syncthreads();

        if (t < 255) {
            if (tid == 0) {
                __hip_atomic_fetch_add(mycnt, 1u, __ATOMIC_RELEASE, __HIP_MEMORY_SCOPE_AGENT);
                while (__hip_atomic_load(mycnt, __ATOMIC_ACQUIRE, __HIP_MEMORY_SCOPE_AGENT) <
                       16u * (unsigned)(t + 1))
                    __builtin_amdgcn_s_sleep(4);
            }
            __syncthreads();
        }
    }
    cbuf[cidx] = cst;
}

// ---------------------------------------------------------------------------
__global__ __launch_bounds__(256) void out_proj(const float* __restrict__ lstm,
                                                const float* __restrict__ wout,
                                                const float* __restrict__ bout,
                                                float* __restrict__ feats) {
    __shared__ __align__(16) float hrow[16 * 512];
    int tid = threadIdx.x;
    size_t m0 = (size_t)blockIdx.x * 16;
    {
        const float4* src = (const float4*)(lstm + m0 * 512);
        float4* dst = (float4*)hrow;
        for (int i = tid; i < 2048; i += 256) dst[i] = src[i];
    }
    __syncthreads();
    int n = tid & 127, rh = tid >> 7;
    int nn = (n < NT_) ? n : 0;
    float acc[8];
#pragma unroll
    for (int rr = 0; rr < 8; rr++) acc[rr] = 0.f;
    const float* wrow = wout + (size_t)nn * 512;
    for (int k = 0; k < 512; k += 4) {
        float4 wv = *(const float4*)&wrow[k];
#pragma unroll
        for (int rr = 0; rr < 8; ++rr) {
            float4 hv = *(const float4*)&hrow[(rh * 8 + rr) * 512 + k];
            acc[rr] += wv.x * hv.x + wv.y * hv.y + wv.z * hv.z + wv.w * hv.w;
        }
    }
    if (n < NT_) {
        float bb = bout[n];
#pragma unroll
        for (int rr = 0; rr < 8; ++rr)
            feats[(m0 + rh * 8 + rr) * NT_ + n] = acc[rr] + bb;
    }
}

// ---------------------------------------------------------------------------
__global__ __launch_bounds__(128) void viterbi(const float* __restrict__ feats,
                                               const float* __restrict__ trans,
                                               float* __restrict__ out) {
    int b = blockIdx.x, tid = threadIdx.x;
    __shared__ float fvbuf[2][80];
    __shared__ float termbuf[80];
    __shared__ unsigned char bptr[256][NT_];

    float trr[NT_];
    if (tid < NT_) {
#pragma unroll
        for (int p = 0; p < NT_; p++) trr[p] = trans[tid * NT_ + p];
    }
    if (tid < 80) fvbuf[0][tid] = (tid == START_) ? 0.f : NEGV;
    __syncthreads();

    const float* fb = feats + (size_t)b * T_ * NT_;
    for (int t = 0; t < T_; ++t) {
        int par = t & 1;
        if (tid < NT_) {
            float feat = fb[t * NT_ + tid];
            const float* fv = fvbuf[par];
            float best = fv[0] + trr[0];
            int arg = 0;
#pragma unroll
            for (int p = 1; p < NT_; ++p) {
                float sc = fv[p] + trr[p];
                if (sc > best) { best = sc; arg = p; }
            }
            bptr[t][tid] = (unsigned char)arg;
            fvbuf[1 - par][tid] = best + feat;
        }
        __syncthreads();
    }
    if (tid < NT_) termbuf[tid] = fvbuf[0][tid] + trans[STOP_ * NT_ + tid];
    __syncthreads();
    if (tid == 0) {
        float best = termbuf[0];
        int arg = 0;
        for (int p = 1; p < NT_; ++p)
            if (termbuf[p] > best) { best = termbuf[p]; arg = p; }
        out[b] = best;
        int tag = arg;
        float* pout = out + 128 + (size_t)b * T_;
        for (int t = T_ - 1; t >= 0; --t) {
            pout[t] = (float)tag;
            tag = bptr[t][tag];
        }
    }
}

// ---------------------------------------------------------------------------
extern "C" void kernel_launch(void* const* d_in, const int* in_sizes, int n_in,
                              void* d_out, int out_size, void* d_ws, size_t ws_size,
                              hipStream_t stream) {
    const int*   ids   = (const int*)  d_in[0];
    const float* emb   = (const float*)d_in[1];
    const float* whh_f = (const float*)d_in[3];
    const float* bih_f = (const float*)d_in[4];
    const float* bhh_f = (const float*)d_in[5];
    const float* whh_b = (const float*)d_in[7];
    const float* bih_b = (const float*)d_in[8];
    const float* bhh_b = (const float*)d_in[9];
    const float* h0    = (const float*)d_in[10];
    const float* c0    = (const float*)d_in[11];
    const float* wout  = (const float*)d_in[12];
    const float* bout  = (const float*)d_in[13];
    const float* trans = (const float*)d_in[14];
    const float* wih_f = (const float*)d_in[2];
    const float* wih_b = (const float*)d_in[6];

    char* ws = (char*)d_ws;
    unsigned short* A3  = (unsigned short*)(ws + OFF_A3);
    unsigned short* B3T = (unsigned short*)(ws + OFF_B3T);
    float* XPROJ        = (float*)(ws + OFF_XPROJ);
    float* LSTM         = (float*)(ws + OFF_LSTM);
    float* HBUF         = (float*)(ws + OFF_HBUF);
    float* CBUF         = (float*)(ws + OFF_CBUF);
    unsigned char* CNT  = (unsigned char*)(ws + OFF_CNT);
    float* FEATS        = (float*)(ws + OFF_FEATS);   // aliases A3 (dead by then)

    init_cnt <<<1,     64,  0, stream>>>((unsigned int*)CNT);
    build_a3 <<<32768, 256, 0, stream>>>(ids, emb, A3);
    build_b3t<<<2048,  256, 0, stream>>>(wih_f, wih_b, B3T);
    for (int c = 0; c < 4; ++c) {
        gemm_chunk<<<1024, 256, 0, stream>>>(A3, B3T, XPROJ, c * 64);
        lstm_rec  <<<256,  256, 0, stream>>>(XPROJ, whh_f, whh_b, bih_f, bhh_f, bih_b, bhh_b,
                                             h0, c0, LSTM, HBUF, CBUF, CNT, c * 64);
    }
    out_proj<<<2048, 256, 0, stream>>>(LSTM, wout, bout, FEATS);
    viterbi <<<128,  128, 0, stream>>>(FEATS, trans, (float*)d_out);
}

// Round 3
// 2099.195 us; speedup vs baseline: 2.1850x; 2.1850x over previous
//
#include <hip/hip_runtime.h>
#include <hip/hip_bf16.h>
#include <stdint.h>

// ---------------------------------------------------------------------------
// BiLSTM-CRF on MI355X.  B=128, T=256, E=256, H2=256, NTAGS=76.
//   init_cnt   : zero cluster counters
//   build_a3   : embedding gather + split-bf16 (hi,hi,lo) A [32768 x 768]
//   build_b3t  : Wih both dirs split-bf16 (hi,lo,hi) B^T    [2048 x 768]
//   gemm_chunk : bf16 MFMA GEMM (3-term compensated == fp32-class) computing
//                xproj for a 64-step time chunk (both dirs) -> 64 MiB buffer
//   lstm_rec   : fp32 recurrence, 64 steps/launch. 256 WGs = 16 clusters x 16
//                hidden-slices; Whh slice register-resident; h exchanged via
//                LLC-direct (sc0 sc1) accesses; RELAXED flag counter -- no
//                acquire/release => no per-step L2 writeback/invalidate.
//   out_proj   : feats = lstm_out @ W_out^T + b_out (fp32)
//   viterbi    : per-batch decode + backtrack -> score + path
// ---------------------------------------------------------------------------

#define T_      256
#define NT_     76
#define K3_     768
#define START_  74
#define STOP_   75
#define NEGV    (-10000.0f)

// ws offsets (bytes)
#define OFF_A3    ((size_t)0)                         // u16 [32768][768]   48 MiB
#define OFF_B3T   (OFF_A3    + (size_t)50331648)      // u16 [2048][768]     3 MiB
#define OFF_XPROJ (OFF_B3T   + (size_t)3145728)       // f32 [2][128][64][1024] 64 MiB
#define OFF_LSTM  (OFF_XPROJ + (size_t)67108864)      // f32 [32768][512]   64 MiB
#define OFF_HBUF  (OFF_LSTM  + (size_t)67108864)      // f32 [2][16][256u][16b] 512 KiB
#define OFF_CBUF  (OFF_HBUF  + (size_t)524288)        // f32 [2][128][256] 256 KiB
#define OFF_CNT   (OFF_CBUF  + (size_t)262144)        // u32 x16, 256B stride
#define OFF_FEATS OFF_A3                              // f32 [32768][76] aliases A3

typedef __attribute__((ext_vector_type(8))) short short8;
typedef __attribute__((ext_vector_type(4))) float float4v;
typedef const __attribute__((address_space(1))) unsigned int gas_uint;
typedef __attribute__((address_space(3))) unsigned int las_uint;

__device__ __forceinline__ unsigned short f2bf(float x) {
    unsigned int u = __float_as_uint(x);
    u = (u + 0x7fffu + ((u >> 16) & 1u)) >> 16;   // RNE
    return (unsigned short)u;
}
__device__ __forceinline__ float bf2f(unsigned short h) {
    return __uint_as_float(((unsigned int)h) << 16);
}
__device__ __forceinline__ void gl_lds16(const void* g, void* l) {
    __builtin_amdgcn_global_load_lds((gas_uint*)g, (las_uint*)l, 16, 0, 0);
}
// LLC-direct (bypass L1+L2, coherent across XCDs) access helpers.
__device__ __forceinline__ float4v llc_ld4(const float* p) {
    float4v r;
    asm volatile("global_load_dwordx4 %0, %1, off sc0 sc1" : "=v"(r) : "v"(p) : "memory");
    return r;
}
__device__ __forceinline__ void llc_st(float* p, float v) {
    asm volatile("global_store_dword %0, %1, off sc0 sc1" :: "v"(p), "v"(v) : "memory");
}
__device__ __forceinline__ void wait_vm0() { asm volatile("s_waitcnt vmcnt(0)" ::: "memory"); }

__global__ __launch_bounds__(64) void init_cnt(unsigned int* cnt) {
    if (threadIdx.x < 16) cnt[threadIdx.x * 64] = 0u;   // 256B stride
}

// ---------------------------------------------------------------------------
__global__ __launch_bounds__(256) void build_a3(const int* __restrict__ ids,
                                                const float* __restrict__ emb,
                                                unsigned short* __restrict__ a3) {
    int m = blockIdx.x, k = threadIdx.x;
    int id = ids[m];
    float x = emb[(size_t)id * 256 + k];
    unsigned short hu = f2bf(x);
    unsigned short lu = f2bf(x - bf2f(hu));
    size_t base = (size_t)m * K3_;
    a3[base + k]       = hu;
    a3[base + 256 + k] = hu;
    a3[base + 512 + k] = lu;
}

__global__ __launch_bounds__(256) void build_b3t(const float* __restrict__ wf,
                                                 const float* __restrict__ wb,
                                                 unsigned short* __restrict__ b3t) {
    int n = blockIdx.x, k = threadIdx.x;
    const float* w = (n < 1024) ? wf : wb;
    int j = n & 1023;
    float x = w[(size_t)j * 256 + k];
    unsigned short hu = f2bf(x);
    unsigned short lu = f2bf(x - bf2f(hu));
    size_t base = (size_t)n * K3_;
    b3t[base + k]       = hu;
    b3t[base + 256 + k] = lu;
    b3t[base + 512 + k] = hu;
}

// ---------------------------------------------------------------------------
// xproj chunk GEMM.  grid = 2 dirs x 64 m-tiles x 8 n-tiles = 1024 blocks.
// ---------------------------------------------------------------------------
__global__ __launch_bounds__(256) void gemm_chunk(const unsigned short* __restrict__ A,
                                                  const unsigned short* __restrict__ Bt,
                                                  float* __restrict__ C, int t0) {
    __shared__ __align__(16) unsigned short As[128 * 64];
    __shared__ __align__(16) unsigned short Bs[128 * 64];
    int tid = threadIdx.x, bx = blockIdx.x;
    int d = bx >> 9, rem = bx & 511;
    int tm = rem >> 3, tn = rem & 7;
    int m0 = tm * 128, n0l = tn * 128;
    int tbase = d ? (192 - t0) : t0;
    int lane = tid & 63, wave = tid >> 6;
    int wm = (wave & 1) * 64, wn = (wave >> 1) * 64;
    int quad = lane >> 4, r16 = lane & 15;

    float4v acc[4][4];
#pragma unroll
    for (int i = 0; i < 4; i++)
#pragma unroll
        for (int j = 0; j < 4; j++) acc[i][j] = (float4v){0.f, 0.f, 0.f, 0.f};

    for (int kt = 0; kt < 12; ++kt) {
        int k0 = kt * 64;
#pragma unroll
        for (int i = 0; i < 4; ++i) {
            int c = i * 256 + tid;
            int row = c >> 3, col = c & 7;
            int rowm = m0 + row;
            int arow = (rowm >> 6) * 256 + tbase + (rowm & 63);
            int brow = d * 1024 + n0l + row;
            gl_lds16(A  + (size_t)arow * K3_ + k0 + col * 8, (unsigned short*)As + (size_t)c * 8);
            gl_lds16(Bt + (size_t)brow * K3_ + k0 + col * 8, (unsigned short*)Bs + (size_t)c * 8);
        }
        __syncthreads();
#pragma unroll
        for (int kk = 0; kk < 64; kk += 32) {
            short8 a[4], b[4];
#pragma unroll
            for (int i = 0; i < 4; i++) {
                a[i] = *(const short8*)&As[(wm + i * 16 + r16) * 64 + kk + quad * 8];
                b[i] = *(const short8*)&Bs[(wn + i * 16 + r16) * 64 + kk + quad * 8];
            }
#pragma unroll
            for (int i = 0; i < 4; i++)
#pragma unroll
                for (int j = 0; j < 4; j++)
                    acc[i][j] = __builtin_amdgcn_mfma_f32_16x16x32_bf16(a[i], b[j], acc[i][j], 0, 0, 0);
        }
        __syncthreads();
    }
#pragma unroll
    for (int i = 0; i < 4; i++)
#pragma unroll
        for (int j = 0; j < 4; j++)
#pragma unroll
            for (int r = 0; r < 4; r++) {
                int ml = wm + i * 16 + quad * 4 + r;
                int rowm = m0 + ml;
                int b = rowm >> 6, tl = rowm & 63;
                int n = n0l + wn + j * 16 + r16;
                C[(((size_t)(d * 128 + b)) * 64 + tl) * 1024 + n] = acc[i][j][r];
            }
}

// ---------------------------------------------------------------------------
// Recurrence, 64 steps per launch.  256 WGs x 256 thr.
// hbuf per-cluster layout: [unit 0..255][sample 0..15]  (reader-coalesced).
// ---------------------------------------------------------------------------
#define HSTR 20

__global__ __launch_bounds__(256) void lstm_rec(
    const float* __restrict__ xproj,
    const float* __restrict__ whh_f, const float* __restrict__ whh_b,
    const float* __restrict__ bih_f, const float* __restrict__ bhh_f,
    const float* __restrict__ bih_b, const float* __restrict__ bhh_b,
    const float* __restrict__ h0,    const float* __restrict__ c0,
    float* __restrict__ lstm_out, float* hbuf, float* cbuf,
    unsigned char* cntbase, int t0) {

    int bx = blockIdx.x;
    int xcd = bx & 7, m8 = bx >> 3;
    int cid = xcd * 2 + (m8 >> 4);           // cluster id [0,16)
    int s   = m8 & 15;                       // hidden-slice [0,16)
    int d   = cid & 1, g = cid >> 1;
    int tid = threadIdx.x;

    // phase-B identity: wave q = k-quarter, lane r = gate*16 + ulocal
    int q = tid >> 6, r = tid & 63;
    int rowB = (r >> 4) * 256 + s * 16 + (r & 15);
    const float* whh = d ? whh_b : whh_f;
    float4 w4[16];
    {
        const float4* wp = (const float4*)(whh + (size_t)rowB * 256 + q * 64);
#pragma unroll
        for (int i = 0; i < 16; i++) w4[i] = wp[i];
    }

    // phase-C identity: (sample b2, unit u2)
    int b2 = tid >> 4, u2 = tid & 15;
    int ug2 = s * 16 + u2;
    int bg2 = g * 16 + b2;
    const float* bih = d ? bih_b : bih_f;
    const float* bhh = d ? bhh_b : bhh_f;
    float bias[4];
#pragma unroll
    for (int gg = 0; gg < 4; gg++) bias[gg] = bih[gg * 256 + ug2] + bhh[gg * 256 + ug2];
    size_t cidx = ((size_t)d * 128 + bg2) * 256 + ug2;
    float cst = (t0 == 0) ? c0[cidx] : cbuf[cidx];

    __shared__ __align__(16) float h_lds[256 * HSTR];
    __shared__ __align__(16) float red[4 * 64 * HSTR];

    unsigned int* mycnt = (unsigned int*)(cntbase + (size_t)cid * 256);
    const size_t HB_PAR = (size_t)16 * 4096;
    size_t hb_c = (size_t)cid * 4096;

    // prefetch xproj for first step
    float xp[4];
    {
        int tloc0 = d ? 63 : 0;
        const float* xb = xproj + (((size_t)(d * 128 + bg2)) * 64 + tloc0) * 1024 + ug2;
#pragma unroll
        for (int gg = 0; gg < 4; gg++) xp[gg] = xb[gg * 256];
    }

    for (int tl = 0; tl < 64; ++tl) {
        int t = t0 + tl;
        int t_src = d ? (255 - t) : t;

        // ---- P1: stage h_t into LDS [k][b]; thread tid owns unit k=tid
        if (t == 0) {
#pragma unroll
            for (int b = 0; b < 16; b++)
                h_lds[tid * HSTR + b] = h0[((size_t)d * 128 + g * 16 + b) * 256 + tid];
        } else {
            const float* hsrc = hbuf + (size_t)(t & 1) * HB_PAR + hb_c + (size_t)tid * 16;
            float4v v0 = llc_ld4(hsrc);
            float4v v1 = llc_ld4(hsrc + 4);
            float4v v2 = llc_ld4(hsrc + 8);
            float4v v3 = llc_ld4(hsrc + 12);
            wait_vm0();
            float4v* dst = (float4v*)&h_lds[tid * HSTR];
            dst[0] = v0; dst[1] = v1; dst[2] = v2; dst[3] = v3;
        }
        __syncthreads();                       // B1

        // ---- P2: partial gates acc[b] = sum_{k in quarter} w[k]*h[k][b]
        float acc[16];
#pragma unroll
        for (int b = 0; b < 16; b++) acc[b] = 0.f;
        const float* hq = h_lds + q * 64 * HSTR;
#pragma unroll
        for (int k4 = 0; k4 < 16; ++k4) {
            float4 wv = w4[k4];
#pragma unroll
            for (int kk = 0; kk < 4; ++kk) {
                float wx = (kk == 0) ? wv.x : (kk == 1) ? wv.y : (kk == 2) ? wv.z : wv.w;
                const float4* hv = (const float4*)(hq + (k4 * 4 + kk) * HSTR);
                float4 ha = hv[0], hb4 = hv[1], hc = hv[2], hd = hv[3];   // broadcast
                acc[0]  += wx * ha.x;  acc[1]  += wx * ha.y;  acc[2]  += wx * ha.z;  acc[3]  += wx * ha.w;
                acc[4]  += wx * hb4.x; acc[5]  += wx * hb4.y; acc[6]  += wx * hb4.z; acc[7]  += wx * hb4.w;
                acc[8]  += wx * hc.x;  acc[9]  += wx * hc.y;  acc[10] += wx * hc.z;  acc[11] += wx * hc.w;
                acc[12] += wx * hd.x;  acc[13] += wx * hd.y;  acc[14] += wx * hd.z;  acc[15] += wx * hd.w;
            }
        }
        {
            float4* rp = (float4*)&red[(q * 64 + r) * HSTR];
            rp[0] = make_float4(acc[0], acc[1], acc[2], acc[3]);
            rp[1] = make_float4(acc[4], acc[5], acc[6], acc[7]);
            rp[2] = make_float4(acc[8], acc[9], acc[10], acc[11]);
            rp[3] = make_float4(acc[12], acc[13], acc[14], acc[15]);
        }
        __syncthreads();                       // B2

        // ---- P3: combine, cell update, publish
        float gate[4];
#pragma unroll
        for (int gg = 0; gg < 4; gg++) {
            int rr = gg * 16 + u2;
            gate[gg] = red[(0 * 64 + rr) * HSTR + b2] + red[(1 * 64 + rr) * HSTR + b2] +
                       red[(2 * 64 + rr) * HSTR + b2] + red[(3 * 64 + rr) * HSTR + b2] +
                       xp[gg] + bias[gg];
        }
        float iv = 1.f / (1.f + expf(-gate[0]));
        float fv = 1.f / (1.f + expf(-gate[1]));
        float gv = tanhf(gate[2]);
        float ov = 1.f / (1.f + expf(-gate[3]));
        cst = fv * cst + iv * gv;
        float hv = ov * tanhf(cst);

        llc_st(hbuf + (size_t)((t + 1) & 1) * HB_PAR + hb_c + (size_t)ug2 * 16 + b2, hv);
        lstm_out[((size_t)bg2 * 256 + t_src) * 512 + d * 256 + ug2] = hv;
        wait_vm0();                            // publish drained to LLC

        // prefetch xproj for next step inside the sync window
        {
            int tln  = (tl < 63) ? tl + 1 : 63;
            int tloc = d ? (63 - tln) : tln;
            const float* xb = xproj + (((size_t)(d * 128 + bg2)) * 64 + tloc) * 1024 + ug2;
#pragma unroll
            for (int gg = 0; gg < 4; gg++) xp[gg] = xb[gg * 256];
        }
        __builtin_amdgcn_s_barrier();          // B3: all publishes drained

        // ---- P4: cluster flag (relaxed only -- no cache maintenance)
        if (t < 255) {
            if (tid == 0) {
                __hip_atomic_fetch_add(mycnt, 1u, __ATOMIC_RELAXED, __HIP_MEMORY_SCOPE_AGENT);
                unsigned tgt = 16u * (unsigned)(t + 1);
                while (__hip_atomic_load(mycnt, __ATOMIC_RELAXED, __HIP_MEMORY_SCOPE_AGENT) < tgt)
                    __builtin_amdgcn_s_sleep(1);
            }
            __builtin_amdgcn_s_barrier();      // B4
        }
    }
    cbuf[cidx] = cst;
}

// ---------------------------------------------------------------------------
__global__ __launch_bounds__(256) void out_proj(const float* __restrict__ lstm,
                                                const float* __restrict__ wout,
                                                const float* __restrict__ bout,
                                                float* __restrict__ feats) {
    __shared__ __align__(16) float hrow[16 * 512];
    int tid = threadIdx.x;
    size_t m0 = (size_t)blockIdx.x * 16;
    {
        const float4* src = (const float4*)(lstm + m0 * 512);
        float4* dst = (float4*)hrow;
        for (int i = tid; i < 2048; i += 256) dst[i] = src[i];
    }
    __syncthreads();
    int n = tid & 127, rh = tid >> 7;
    int nn = (n < NT_) ? n : 0;
    float acc[8];
#pragma unroll
    for (int rr = 0; rr < 8; rr++) acc[rr] = 0.f;
    const float* wrow = wout + (size_t)nn * 512;
    for (int k = 0; k < 512; k += 4) {
        float4 wv = *(const float4*)&wrow[k];
#pragma unroll
        for (int rr = 0; rr < 8; ++rr) {
            float4 hv = *(const float4*)&hrow[(rh * 8 + rr) * 512 + k];
            acc[rr] += wv.x * hv.x + wv.y * hv.y + wv.z * hv.z + wv.w * hv.w;
        }
    }
    if (n < NT_) {
        float bb = bout[n];
#pragma unroll
        for (int rr = 0; rr < 8; ++rr)
            feats[(m0 + rh * 8 + rr) * NT_ + n] = acc[rr] + bb;
    }
}

// ---------------------------------------------------------------------------
__global__ __launch_bounds__(128) void viterbi(const float* __restrict__ feats,
                                               const float* __restrict__ trans,
                                               float* __restrict__ out) {
    int b = blockIdx.x, tid = threadIdx.x;
    __shared__ float fvbuf[2][80];
    __shared__ float termbuf[80];
    __shared__ unsigned char bptr[256][NT_];

    float trr[NT_];
    if (tid < NT_) {
#pragma unroll
        for (int p = 0; p < NT_; p++) trr[p] = trans[tid * NT_ + p];
    }
    if (tid < 80) fvbuf[0][tid] = (tid == START_) ? 0.f : NEGV;
    __syncthreads();

    const float* fb = feats + (size_t)b * T_ * NT_;
    for (int t = 0; t < T_; ++t) {
        int par = t & 1;
        if (tid < NT_) {
            float feat = fb[t * NT_ + tid];
            const float* fv = fvbuf[par];
            float best = fv[0] + trr[0];
            int arg = 0;
#pragma unroll
            for (int p = 1; p < NT_; ++p) {
                float sc = fv[p] + trr[p];
                if (sc > best) { best = sc; arg = p; }
            }
            bptr[t][tid] = (unsigned char)arg;
            fvbuf[1 - par][tid] = best + feat;
        }
        __syncthreads();
    }
    if (tid < NT_) termbuf[tid] = fvbuf[0][tid] + trans[STOP_ * NT_ + tid];
    __syncthreads();
    if (tid == 0) {
        float best = termbuf[0];
        int arg = 0;
        for (int p = 1; p < NT_; ++p)
            if (termbuf[p] > best) { best = termbuf[p]; arg = p; }
        out[b] = best;
        int tag = arg;
        float* pout = out + 128 + (size_t)b * T_;
        for (int t = T_ - 1; t >= 0; --t) {
            pout[t] = (float)tag;
            tag = bptr[t][tag];
        }
    }
}

// ---------------------------------------------------------------------------
extern "C" void kernel_launch(void* const* d_in, const int* in_sizes, int n_in,
                              void* d_out, int out_size, void* d_ws, size_t ws_size,
                              hipStream_t stream) {
    const int*   ids   = (const int*)  d_in[0];
    const float* emb   = (const float*)d_in[1];
    const float* wih_f = (const float*)d_in[2];
    const float* whh_f = (const float*)d_in[3];
    const float* bih_f = (const float*)d_in[4];
    const float* bhh_f = (const float*)d_in[5];
    const float* wih_b = (const float*)d_in[6];
    const float* whh_b = (const float*)d_in[7];
    const float* bih_b = (const float*)d_in[8];
    const float* bhh_b = (const float*)d_in[9];
    const float* h0    = (const float*)d_in[10];
    const float* c0    = (const float*)d_in[11];
    const float* wout  = (const float*)d_in[12];
    const float* bout  = (const float*)d_in[13];
    const float* trans = (const float*)d_in[14];

    char* ws = (char*)d_ws;
    unsigned short* A3  = (unsigned short*)(ws + OFF_A3);
    unsigned short* B3T = (unsigned short*)(ws + OFF_B3T);
    float* XPROJ        = (float*)(ws + OFF_XPROJ);
    float* LSTM         = (float*)(ws + OFF_LSTM);
    float* HBUF         = (float*)(ws + OFF_HBUF);
    float* CBUF         = (float*)(ws + OFF_CBUF);
    unsigned char* CNT  = (unsigned char*)(ws + OFF_CNT);
    float* FEATS        = (float*)(ws + OFF_FEATS);   // aliases A3 (dead by then)

    init_cnt <<<1,     64,  0, stream>>>((unsigned int*)CNT);
    build_a3 <<<32768, 256, 0, stream>>>(ids, emb, A3);
    build_b3t<<<2048,  256, 0, stream>>>(wih_f, wih_b, B3T);
    for (int c = 0; c < 4; ++c) {
        gemm_chunk<<<1024, 256, 0, stream>>>(A3, B3T, XPROJ, c * 64);
        lstm_rec  <<<256,  256, 0, stream>>>(XPROJ, whh_f, whh_b, bih_f, bhh_f, bih_b, bhh_b,
                                             h0, c0, LSTM, HBUF, CBUF, CNT, c * 64);
    }
    out_proj<<<2048, 256, 0, stream>>>(LSTM, wout, bout, FEATS);
    viterbi <<<128,  128, 0, stream>>>(FEATS, trans, (float*)d_out);
}